// Round 7
// baseline (246.802 us; speedup 1.0000x reference)
//
#include <hip/hip_runtime.h>
#include <stdint.h>

// S6Layer on MI355X. B=8, L=4096, DM=256, DI=384, DS=8, CHUNK=32.
// R7 GEMM: ALL staging via pinned global_load_lds (R2-R6 proved compiler sinks
// any VGPR-destination prefetch; R6's inline-asm loads are unsound), LDS
// double-buffered BK=64 chunks, next chunk issued BEFORE computing current so
// the __syncthreads drain waits only ~300 residual cycles instead of ~900
// (A streams from HBM; per-XCD L2 4MB << 25MB). 64KB LDS -> 2 blocks/CU.
#define B_  8
#define L_  4096
#define DM  256
#define DI  384
#define DS  8
#define M_  (B_*L_)   // 32768 tokens

typedef float f32x4 __attribute__((ext_vector_type(4)));
typedef short s16x8 __attribute__((ext_vector_type(8)));

#define AS1(p) ((__attribute__((address_space(1))) void*)(p))
#define AS3(p) ((__attribute__((address_space(3))) void*)(p))

__device__ __forceinline__ unsigned short f2bf(float f) {
  union { float f; uint32_t u; } v; v.f = f;
  uint32_t r = v.u + 0x7FFFu + ((v.u >> 16) & 1u);   // RNE
  return (unsigned short)(r >> 16);
}
__device__ __forceinline__ float bf2f(unsigned short h) {
  union { uint32_t u; float f; } v; v.u = ((uint32_t)h) << 16;
  return v.f;
}
__device__ __forceinline__ float silu_f(float x) { return x / (1.f + __expf(-x)); }

// ---------------- weight fp32 -> bf16 ----------------
__global__ __launch_bounds__(256) void cvt_kernel(
    const float* __restrict__ w0, const float* __restrict__ w1, const float* __restrict__ w2,
    unsigned short* __restrict__ o0, unsigned short* __restrict__ o1, unsigned short* __restrict__ o2) {
  int i = blockIdx.x * 256 + threadIdx.x;
  if (i < 3*DI*DM) o0[i] = f2bf(w0[i]);
  if (i < DI*DI)   o1[i] = f2bf(w1[i]);
  if (i < DM*DI)   o2[i] = f2bf(w2[i]);
}

// ---------------- layernorm: one wave per token ----------------
__global__ __launch_bounds__(256) void ln_kernel(
    const float* __restrict__ x, const float* __restrict__ gamma, const float* __restrict__ beta,
    unsigned short* __restrict__ xn) {
  int token = blockIdx.x * 4 + (threadIdx.x >> 6);
  int lane  = threadIdx.x & 63;
  const float4 v = *(const float4*)(x + (size_t)token*DM + lane*4);
  float s  = v.x + v.y + v.z + v.w;
  float ss = v.x*v.x + v.y*v.y + v.z*v.z + v.w*v.w;
  #pragma unroll
  for (int off = 32; off > 0; off >>= 1) {
    s  += __shfl_xor(s,  off, 64);
    ss += __shfl_xor(ss, off, 64);
  }
  float mean = s * (1.f/DM);
  float var  = ss * (1.f/DM) - mean*mean;
  float rstd = rsqrtf(var + 1e-5f);
  const float4 g = *(const float4*)(gamma + lane*4);
  const float4 b = *(const float4*)(beta  + lane*4);
  ushort4 o;
  o.x = f2bf((v.x - mean)*rstd*g.x + b.x);
  o.y = f2bf((v.y - mean)*rstd*g.y + b.y);
  o.z = f2bf((v.z - mean)*rstd*g.z + b.z);
  o.w = f2bf((v.w - mean)*rstd*g.w + b.w);
  *(ushort4*)(xn + (size_t)token*DM + lane*4) = o;
}

// ---------------- double-buffered pinned-staging MFMA GEMM ----------------
// C[M,N] = A[M,K] @ Bw[N,K]^T (+ epilogue). 128x128 tile, 256 thr (2x2 waves,
// 64x64/wave, 4x4 of 16x16x32). K in CH chunks of 64. LDS layout (64KB):
//   A bufs: [0,8192)+[8192,16384) elems ; B bufs: [16384,24576)+[24576,32768)
// Chunk-slot XOR swizzle (R1-verified): LDS slot c holds global 16B-chunk
// ((c&7)^(row&7)) of row c>>3; fragment read uses qs=(h*4+fq)^(r&7) -> b128
// reads spread over all banks at 2-way (free, m136).
template<int EPI, int CH>
__global__ __launch_bounds__(256, 2) void gemm_db(
    const unsigned short* __restrict__ A,   // [M,K] bf16
    const unsigned short* __restrict__ Bw,  // [N,K] bf16
    const float* __restrict__ bias,         // [N]
    unsigned short* __restrict__ o_xp, unsigned short* __restrict__ o_z,
    unsigned short* __restrict__ o_dtin,    // EPI=1
    unsigned short* __restrict__ o_bf,      // EPI=2
    const float* __restrict__ resid, float* __restrict__ o_f)  // EPI=3
{
  constexpr int K = CH * 64;
  __shared__ unsigned short smem[32768];    // 64 KB

  const int t    = threadIdx.x;
  const int lane = t & 63;
  const int w    = t >> 6;
  const int wm   = (w & 1) * 64;
  const int wn   = (w >> 1) * 64;
  const int fr   = lane & 15;
  const int fq   = lane >> 4;
  const int mbase = blockIdx.x * 128;
  const int nbase = blockIdx.y * 128;

  // per-thread staging descriptors (4 A-chunks + 4 B-chunks per volley)
  const unsigned short* gA[4];
  const unsigned short* gB[4];
  int ldso[4];
  #pragma unroll
  for (int i = 0; i < 4; ++i) {
    int c   = i*256 + t;
    int row = c >> 3;                 // 8 chunks per 64-elem row
    int qs  = (c & 7) ^ (row & 7);
    gA[i] = A  + (size_t)(mbase + row)*K + qs*8;
    gB[i] = Bw + (size_t)(nbase + row)*K + qs*8;
    ldso[i] = c * 8;
  }

  auto issue = [&](int chunk) {
    const int buf = (chunk & 1) * 8192;
    #pragma unroll
    for (int i = 0; i < 4; ++i)
      __builtin_amdgcn_global_load_lds(AS1(gA[i] + chunk*64), AS3(smem + buf + ldso[i]), 16, 0, 0);
    #pragma unroll
    for (int i = 0; i < 4; ++i)
      __builtin_amdgcn_global_load_lds(AS1(gB[i] + chunk*64), AS3(smem + 16384 + buf + ldso[i]), 16, 0, 0);
  };

  f32x4 acc[4][4];
  #pragma unroll
  for (int mi = 0; mi < 4; ++mi)
    #pragma unroll
    for (int ni = 0; ni < 4; ++ni) acc[mi][ni] = (f32x4){0.f, 0.f, 0.f, 0.f};

  issue(0);
  __syncthreads();                 // chunk 0 resident

  #pragma unroll
  for (int c = 0; c < CH; ++c) {
    if (c + 1 < CH) issue(c + 1);  // pinned loads fly during compute of c
    const unsigned short* sA = smem + (c & 1)*8192;
    const unsigned short* sB = smem + 16384 + (c & 1)*8192;
    #pragma unroll
    for (int h = 0; h < 2; ++h) {
      s16x8 af[4], bfr[4];
      #pragma unroll
      for (int mi = 0; mi < 4; ++mi) {
        int r  = wm + mi*16 + fr;
        int qs = (h*4 + fq) ^ (r & 7);
        af[mi] = *(const s16x8*)(sA + r*64 + qs*8);
      }
      #pragma unroll
      for (int ni = 0; ni < 4; ++ni) {
        int r  = wn + ni*16 + fr;
        int qs = (h*4 + fq) ^ (r & 7);
        bfr[ni] = *(const s16x8*)(sB + r*64 + qs*8);
      }
      #pragma unroll
      for (int mi = 0; mi < 4; ++mi)
        #pragma unroll
        for (int ni = 0; ni < 4; ++ni)
          acc[mi][ni] = __builtin_amdgcn_mfma_f32_16x16x32_bf16(af[mi], bfr[ni], acc[mi][ni], 0, 0, 0);
    }
    __syncthreads();               // drain: chunk c+1 issued ~600cyc ago -> short residual
  }

  // ---- epilogue: C layout per 16x16 tile: col=fr, row=fq*4+r (m89) ----
  if constexpr (EPI == 3) {
    #pragma unroll
    for (int ni = 0; ni < 4; ++ni) {
      int gn = nbase + wn + ni*16 + fr;
      float bv = bias[gn];
      #pragma unroll
      for (int mi = 0; mi < 4; ++mi) {
        int gm0 = mbase + wm + mi*16 + fq*4;
        #pragma unroll
        for (int r = 0; r < 4; ++r) {
          size_t gm = (size_t)(gm0 + r);
          o_f[gm*DM + gn] = acc[mi][ni][r] + bv + resid[gm*DM + gn];
        }
      }
    }
  } else {
    // bf16: activation in-register, stage 128x128 tile in smem (pad 136),
    // read back 16B/lane rows -> 256B-contiguous stores. (R3-verified)
    const bool do_silu = (EPI == 1) && (blockIdx.y < 6);   // panels 0-5 = xp,z
    #pragma unroll
    for (int ni = 0; ni < 4; ++ni) {
      int cn = wn + ni*16 + fr;
      float bv = bias[nbase + cn];
      #pragma unroll
      for (int mi = 0; mi < 4; ++mi) {
        int rm0 = wm + mi*16 + fq*4;
        #pragma unroll
        for (int r = 0; r < 4; ++r) {
          float cval = acc[mi][ni][r] + bv;
          if constexpr (EPI == 1) { if (do_silu) cval = silu_f(cval); }
          else                    { cval = (cval > 20.f) ? cval : log1pf(__expf(cval)); }
          smem[(rm0 + r)*136 + cn] = f2bf(cval);
        }
      }
    }
    __syncthreads();
    unsigned short* dst;
    int colbase;
    if constexpr (EPI == 1) {
      int p = blockIdx.y;                       // 0..8
      dst = (p < 3) ? o_xp : (p < 6) ? o_z : o_dtin;
      colbase = (p % 3) * 128;
    } else {
      dst = o_bf; colbase = nbase;
    }
    const int rr = t >> 4, cc = (t & 15) * 8;
    #pragma unroll
    for (int it = 0; it < 8; ++it) {
      int row = rr + it*16;
      s16x8 v = *(const s16x8*)(smem + row*136 + cc);
      *(s16x8*)(dst + (size_t)(mbase + row)*DI + colbase + cc) = v;
    }
  }
}

// ---------------- chunked selective scan ----------------
__global__ __launch_bounds__(384) void scan_kernel(
    const unsigned short* __restrict__ xp, const unsigned short* __restrict__ dt,
    const unsigned short* __restrict__ zb, const float* __restrict__ A_log,
    const float* __restrict__ D_vec, unsigned short* __restrict__ yz) {
  int g  = blockIdx.x;
  int di = threadIdx.x;
  size_t base = (size_t)g * 32 * DI + di;
  float a[DS];
  #pragma unroll
  for (int s = 0; s < DS; ++s) a[s] = -__expf(A_log[di*DS + s]);
  float Dv = D_vec[di];
  float h[DS] = {0.f,0.f,0.f,0.f,0.f,0.f,0.f,0.f};
  for (int tt = 0; tt < 32; ++tt) {
    size_t idx = base + (size_t)tt * DI;
    float xv  = bf2f(xp[idx]);
    float dtv = bf2f(dt[idx]);
    float y = 0.f;
    #pragma unroll
    for (int s = 0; s < DS; ++s) {
      h[s] = h[s] * __expf(dtv * a[s]) + xv;
      y += h[s];
    }
    float zv = bf2f(zb[idx]);
    yz[idx] = f2bf(y * zv + xv * Dv);
  }
}

extern "C" void kernel_launch(void* const* d_in, const int* in_sizes, int n_in,
                              void* d_out, int out_size, void* d_ws, size_t ws_size,
                              hipStream_t stream) {
  const float* x     = (const float*)d_in[0];
  const float* gamma = (const float*)d_in[1];
  const float* beta  = (const float*)d_in[2];
  const float* W_in  = (const float*)d_in[3];
  const float* b_in  = (const float*)d_in[4];
  const float* W_dt  = (const float*)d_in[5];
  const float* b_dt  = (const float*)d_in[6];
  const float* A_log = (const float*)d_in[7];
  const float* D_vec = (const float*)d_in[8];
  const float* W_out = (const float*)d_in[9];
  const float* b_out = (const float*)d_in[10];
  float* out = (float*)d_out;

  char* ws = (char*)d_ws;
  size_t off = 0;
  auto alloc = [&](size_t bytes) -> char* {
    char* p = ws + off; off += (bytes + 255) & ~(size_t)255; return p;
  };
  unsigned short* xn    = (unsigned short*)alloc((size_t)M_*DM*2);
  unsigned short* xpb   = (unsigned short*)alloc((size_t)M_*DI*2);
  unsigned short* zb    = (unsigned short*)alloc((size_t)M_*DI*2);
  unsigned short* dtin  = (unsigned short*)alloc((size_t)M_*DI*2);
  unsigned short* dtb   = (unsigned short*)alloc((size_t)M_*DI*2);
  unsigned short* yzb   = dtin;   // dtin dead after GEMM2 -> reuse for yz
  unsigned short* winb  = (unsigned short*)alloc((size_t)3*DI*DM*2);
  unsigned short* wdtb  = (unsigned short*)alloc((size_t)DI*DI*2);
  unsigned short* woutb = (unsigned short*)alloc((size_t)DM*DI*2);

  cvt_kernel<<<dim3((3*DI*DM + 255)/256), 256, 0, stream>>>(W_in, W_dt, W_out, winb, wdtb, woutb);
  ln_kernel<<<dim3(M_/4), 256, 0, stream>>>(x, gamma, beta, xn);
  // GEMM1: xn[M,256] @ W_in[1152,256]^T -> silu(xp), silu(z), dtin
  gemm_db<1, 4><<<dim3(M_/128, (3*DI)/128), 256, 0, stream>>>(
      xn, winb, b_in, xpb, zb, dtin, nullptr, nullptr, nullptr);
  // GEMM2: dtin[M,384] @ W_dt[384,384]^T ; softplus -> dt
  gemm_db<2, 6><<<dim3(M_/128, DI/128), 256, 0, stream>>>(
      dtin, wdtb, b_dt, nullptr, nullptr, nullptr, dtb, nullptr, nullptr);
  // scan -> yz = y*z + xp*D
  scan_kernel<<<dim3(M_/32), DI, 0, stream>>>(xpb, dtb, zb, A_log, D_vec, yzb);
  // GEMM3: yz[M,384] @ W_out[256,384]^T + b_out + residual -> out (fp32)
  gemm_db<3, 6><<<dim3(M_/128, DM/128), 256, 0, stream>>>(
      yzb, woutb, b_out, nullptr, nullptr, nullptr, nullptr, x, out);
}